// Round 3
// baseline (416.609 us; speedup 1.0000x reference)
//
#include <hip/hip_runtime.h>
#include <stdint.h>

#define SEQ 256
#define BATCH 32
#define IN_DIM 1024
#define HID 64
#define NPAD 1280
#define ROWS (SEQ*BATCH)   // 8192

// workspace byte offsets (all 256B aligned)
#define XBF_OFF   0
#define WBF_OFF   16777216
#define BB_OFF    19398656
#define GATE_OFF  19403776
#define Y_OFF     19534848
// total ws use: 61,477,888 bytes

typedef __attribute__((ext_vector_type(8))) short short8;
typedef __attribute__((ext_vector_type(4))) float floatx4;

static __device__ __forceinline__ short f2bf(float f) {
  union { float f; uint32_t u; } a; a.f = f;
  uint32_t r = (a.u + 0x7FFFu + ((a.u >> 16) & 1u)) >> 16;  // RNE
  return (short)r;
}

// ---------------- prep: fp32 -> bf16 for X, concat+convert weights, concat bias ----------------
__global__ void prep_kernel(const float* __restrict__ X,
                            const float* __restrict__ Wk, const float* __restrict__ bk,
                            const float* __restrict__ Wv, const float* __restrict__ bv,
                            const float* __restrict__ Wg, const float* __restrict__ bg,
                            const float* __restrict__ Wq, const float* __restrict__ bq,
                            short* __restrict__ Xbf, short* __restrict__ Wbf,
                            float* __restrict__ bb)
{
  int64_t idx = (int64_t)blockIdx.x * blockDim.x + threadIdx.x;
  int64_t stride = (int64_t)gridDim.x * blockDim.x;
  const int64_t NX4 = (int64_t)ROWS * IN_DIM / 4;
  for (int64_t i = idx; i < NX4; i += stride) {
    float4 x = ((const float4*)X)[i];
    short4 s4;
    s4.x = f2bf(x.x); s4.y = f2bf(x.y); s4.z = f2bf(x.z); s4.w = f2bf(x.w);
    ((short4*)Xbf)[i] = s4;
  }
  const int64_t NW4 = (int64_t)NPAD * IN_DIM / 4;
  for (int64_t i = idx; i < NW4; i += stride) {
    int64_t e = i * 4;
    int r = (int)(e >> 10);
    int k = (int)(e & 1023);
    float4 x;
    if (r < 576)       x = *(const float4*)(Wk + (int64_t)r*1024 + k);
    else if (r < 1152) x = *(const float4*)(Wv + (int64_t)(r-576)*1024 + k);
    else if (r < 1216) x = *(const float4*)(Wq + (int64_t)(r-1152)*1024 + k);
    else               x = make_float4(0.f, 0.f, 0.f, 0.f);   // gate cols unused (fp32 gate kernel)
    short4 s4;
    s4.x = f2bf(x.x); s4.y = f2bf(x.y); s4.z = f2bf(x.z); s4.w = f2bf(x.w);
    ((short4*)Wbf)[i] = s4;
  }
  for (int64_t i = idx; i < NPAD; i += stride) {
    int r = (int)i; float v;
    if (r < 576)       v = bk[r];
    else if (r < 1152) v = bv[r - 576];
    else if (r < 1216) v = bq[r - 1152];
    else               v = 0.f;
    bb[r] = v;
  }
}

// ---------------- GEMM: Y[8192,1280] = Xbf @ Wbf^T + bb (bf16 MFMA, fp32 accum) ----------------
// 64x64 tile, BK=32, 256 threads (4 waves). Wave w -> N-subtile w; 4 M-subtiles each.
__global__ __launch_bounds__(256) void gemm_kernel(
    const short* __restrict__ Xbf,
    const short* __restrict__ Wbf,
    const float* __restrict__ bb,
    float* __restrict__ Y)
{
  __shared__ short8 AsV[256];  // 64 rows x 32 k, bf16
  __shared__ short8 BsV[256];
  short* As = (short*)AsV;
  short* Bs = (short*)BsV;

  const int tid  = threadIdx.x;
  const int lane = tid & 63;
  const int wv   = tid >> 6;     // 0..3
  const int quad = lane >> 4;    // 0..3
  const int cl   = lane & 15;
  const int m0 = blockIdx.y * 64;
  const int n0 = blockIdx.x * 64;

  // staging: each thread moves 16B (8 bf16) of A and of B per k-step
  const int srow = tid >> 2;         // 0..63
  const int scol = (tid & 3) * 8;    // 0,8,16,24
  const short* gA = Xbf + (int64_t)(m0 + srow) * IN_DIM + scol;
  const short* gB = Wbf + (int64_t)(n0 + srow) * IN_DIM + scol;
  short8* lA = (short8*)&As[srow * 32 + scol];
  short8* lB = (short8*)&Bs[srow * 32 + scol];

  floatx4 acc[4];
#pragma unroll
  for (int i = 0; i < 4; i++) acc[i] = (floatx4){0.f, 0.f, 0.f, 0.f};

  for (int ks = 0; ks < IN_DIM; ks += 32) {
    short8 ra = *(const short8*)(gA + ks);
    short8 rb = *(const short8*)(gB + ks);
    *lA = ra;
    *lB = rb;
    __syncthreads();
    short8 bfrag = *(const short8*)(&Bs[(wv * 16 + cl) * 32 + quad * 8]);
#pragma unroll
    for (int mt = 0; mt < 4; mt++) {
      short8 afrag = *(const short8*)(&As[(mt * 16 + cl) * 32 + quad * 8]);
      acc[mt] = __builtin_amdgcn_mfma_f32_16x16x32_bf16(afrag, bfrag, acc[mt], 0, 0, 0);
    }
    __syncthreads();
  }

  const int col = n0 + wv * 16 + cl;
  const float bias = bb[col];
#pragma unroll
  for (int mt = 0; mt < 4; mt++) {
#pragma unroll
    for (int r = 0; r < 4; r++) {
      int row = m0 + mt * 16 + quad * 4 + r;
      Y[(int64_t)row * NPAD + col] = acc[mt][r] + bias;
    }
  }
}

// ---------------- gate (fp32-exact): logits from X,Wg in fp32; top-2 + renormalized weights --------
// One wave per row. Lane l covers elements {i*256 + l*4 .. +3}, i=0..3 (float4, coalesced).
__global__ __launch_bounds__(256) void gate_kernel(
    const float* __restrict__ X,
    const float* __restrict__ Wg, const float* __restrict__ bg,
    float4* __restrict__ gate)
{
  const int lane = threadIdx.x & 63;
  const int row  = blockIdx.x * 4 + (threadIdx.x >> 6);
  const float* x = X + (int64_t)row * IN_DIM;

  float acc[8];
#pragma unroll
  for (int e = 0; e < 8; e++) acc[e] = 0.f;

#pragma unroll
  for (int i = 0; i < 4; i++) {
    const int off = i * 256 + lane * 4;
    float4 xv = *(const float4*)(x + off);
#pragma unroll
    for (int e = 0; e < 8; e++) {
      float4 wv = *(const float4*)(Wg + e * IN_DIM + off);
      acc[e] += xv.x * wv.x + xv.y * wv.y + xv.z * wv.z + xv.w * wv.w;
    }
  }
  // butterfly reduce each expert's partial across the 64 lanes
#pragma unroll
  for (int e = 0; e < 8; e++) {
#pragma unroll
    for (int m = 32; m >= 1; m >>= 1)
      acc[e] += __shfl_xor(acc[e], m);
    acc[e] += bg[e];
  }

  if (lane == 0) {
    int i0 = 0; float v0 = acc[0];
#pragma unroll
    for (int e = 1; e < 8; e++) if (acc[e] > v0) { v0 = acc[e]; i0 = e; }
    int i1 = -1; float v1 = -3.4e38f;
#pragma unroll
    for (int e = 0; e < 8; e++) if (e != i0 && acc[e] > v1) { v1 = acc[e]; i1 = e; }
    float e1 = __expf(v1 - v0);
    float inv = 1.f / (1.f + e1);
    gate[row] = make_float4(__int_as_float(i0), __int_as_float(i1), inv, e1 * inv);
  }
}

// ---------------- recurrence: M register-resident, 2 j-split wgs per batch ----------------
// layout: lane&15 -> i-block (i = 4*(lane&15)+ii), lane>>4 + 4*wave + 32*jblk -> j
// Reference semantics: ALL scatter-adds happen first (slot 0 shared + routed i0,i1,
// dupes accumulate), THEN readout M_out = M[0] + g0*M[i0] + g1*M[i1]. When a routed
// slot IS 0, the unweighted M[0] readout term must include the routed update too —
// DO_SLOT0 adds the update delta to Mc unweighted (fixes R2's absmax=18).
__global__ __launch_bounds__(512) void recur_kernel(
    const float* __restrict__ Y,
    const float4* __restrict__ gate,
    const float* __restrict__ M0,
    float* __restrict__ out)
{
  const int blk  = blockIdx.x;      // 0..63
  const int b    = blk >> 1;
  const int jblk = blk & 1;
  const int tid  = threadIdx.x;
  const int lane = tid & 63;
  const int wv   = tid >> 6;        // 0..7
  const int igrp = lane & 15;
  const int jloc = lane >> 4;
  const int j    = jblk * 32 + wv * 4 + jloc;
  const int ib   = igrp * 4;

  float M[9][4];
  const float* M0b = M0 + (int64_t)b * 9 * 4096;
#pragma unroll
  for (int m = 0; m < 9; m++)
#pragma unroll
    for (int ii = 0; ii < 4; ii++)
      M[m][ii] = M0b[m * 4096 + (ib + ii) * 64 + j];

  float* Mf = out + (int64_t)SEQ * BATCH * HID + (int64_t)b * 9 * 4096;

  // gate prefetch ring, distance 2
  float4 ga = gate[0 * BATCH + b];
  float4 gb = gate[1 * BATCH + b];

  for (int t = 0; t < SEQ; t++) {
    int tp = t + 2; if (tp > SEQ - 1) tp = SEQ - 1;
    float4 gc = gate[tp * BATCH + b];

    const int i0 = __float_as_int(ga.x);
    const int i1 = __float_as_int(ga.y);
    const float g0 = ga.z, g1 = ga.w;

    const float* Yrow = Y + (int64_t)(t * BATCH + b) * NPAD;
    // issue all loads up front (addresses only need the prefetched gate)
    float4 q  = *(const float4*)(Yrow + 1152 + ib);
    float4 k0 = *(const float4*)(Yrow + ib);
    float  v0 = Yrow[576 + j];
    float4 ka = *(const float4*)(Yrow + i0 * 64 + ib);
    float  va = Yrow[576 + i0 * 64 + j];
    float4 kb = *(const float4*)(Yrow + i1 * 64 + ib);
    float  vb = Yrow[576 + i1 * 64 + j];

    float Mc0, Mc1, Mc2, Mc3;
    // shared slot 0: always updated with head 0, read weight 1
    M[0][0] += k0.x * v0; M[0][1] += k0.y * v0; M[0][2] += k0.z * v0; M[0][3] += k0.w * v0;
    Mc0 = M[0][0]; Mc1 = M[0][1]; Mc2 = M[0][2]; Mc3 = M[0][3];

#define DO_SLOT(mm, gw, KK, VV) {                                            \
      M[mm][0] += KK.x * VV; M[mm][1] += KK.y * VV;                          \
      M[mm][2] += KK.z * VV; M[mm][3] += KK.w * VV;                          \
      Mc0 += (gw) * M[mm][0]; Mc1 += (gw) * M[mm][1];                        \
      Mc2 += (gw) * M[mm][2]; Mc3 += (gw) * M[mm][3]; }

    // routed slot == 0: Mc already captured M[0] pre-update; add the delta
    // unweighted (so the "+ M[:,0]" readout term sees the routed update too)
    // plus the gated read of the updated slot.
#define DO_SLOT0(gw, KK, VV) {                                               \
      float d0 = KK.x * VV, d1 = KK.y * VV, d2 = KK.z * VV, d3 = KK.w * VV;  \
      M[0][0] += d0; M[0][1] += d1; M[0][2] += d2; M[0][3] += d3;            \
      Mc0 += d0 + (gw) * M[0][0]; Mc1 += d1 + (gw) * M[0][1];                \
      Mc2 += d2 + (gw) * M[0][2]; Mc3 += d3 + (gw) * M[0][3]; }

    switch (i0) {   // wave-uniform branch
      case 0: DO_SLOT0(g0, ka, va); break;
      case 1: DO_SLOT(1, g0, ka, va); break;
      case 2: DO_SLOT(2, g0, ka, va); break;
      case 3: DO_SLOT(3, g0, ka, va); break;
      case 4: DO_SLOT(4, g0, ka, va); break;
      case 5: DO_SLOT(5, g0, ka, va); break;
      case 6: DO_SLOT(6, g0, ka, va); break;
      default: DO_SLOT(7, g0, ka, va); break;
    }
    switch (i1) {
      case 0: DO_SLOT0(g1, kb, vb); break;
      case 1: DO_SLOT(1, g1, kb, vb); break;
      case 2: DO_SLOT(2, g1, kb, vb); break;
      case 3: DO_SLOT(3, g1, kb, vb); break;
      case 4: DO_SLOT(4, g1, kb, vb); break;
      case 5: DO_SLOT(5, g1, kb, vb); break;
      case 6: DO_SLOT(6, g1, kb, vb); break;
      default: DO_SLOT(7, g1, kb, vb); break;
    }
#undef DO_SLOT
#undef DO_SLOT0

    float part = q.x * Mc0 + q.y * Mc1 + q.z * Mc2 + q.w * Mc3;
    // butterfly reduce over the 16 i-lanes (xor 1,2,4,8 stay within the 16-group)
    part += __int_as_float(__builtin_amdgcn_ds_swizzle(__float_as_int(part), 0x041F));
    part += __int_as_float(__builtin_amdgcn_ds_swizzle(__float_as_int(part), 0x081F));
    part += __int_as_float(__builtin_amdgcn_ds_swizzle(__float_as_int(part), 0x101F));
    part += __int_as_float(__builtin_amdgcn_ds_swizzle(__float_as_int(part), 0x201F));
    if (igrp == 0)
      out[(int64_t)t * (BATCH * HID) + b * HID + j] = part;

    ga = gb; gb = gc;
  }

#pragma unroll
  for (int m = 0; m < 9; m++)
#pragma unroll
    for (int ii = 0; ii < 4; ii++)
      Mf[m * 4096 + (ib + ii) * 64 + j] = M[m][ii];
}

// ---------------- launch ----------------
extern "C" void kernel_launch(void* const* d_in, const int* in_sizes, int n_in,
                              void* d_out, int out_size, void* d_ws, size_t ws_size,
                              hipStream_t stream)
{
  const float* X  = (const float*)d_in[0];
  const float* M0 = (const float*)d_in[1];
  const float* Wk = (const float*)d_in[2];
  const float* bk = (const float*)d_in[3];
  const float* Wv = (const float*)d_in[4];
  const float* bv = (const float*)d_in[5];
  const float* Wg = (const float*)d_in[6];
  const float* bg = (const float*)d_in[7];
  const float* Wq = (const float*)d_in[8];
  const float* bq = (const float*)d_in[9];

  char* ws = (char*)d_ws;
  short*  Xbf  = (short*)(ws + XBF_OFF);
  short*  Wbf  = (short*)(ws + WBF_OFF);
  float*  bb   = (float*)(ws + BB_OFF);
  float4* gate = (float4*)(ws + GATE_OFF);
  float*  Y    = (float*)(ws + Y_OFF);
  float*  out  = (float*)d_out;

  prep_kernel<<<2048, 256, 0, stream>>>(X, Wk, bk, Wv, bv, Wg, bg, Wq, bq, Xbf, Wbf, bb);
  gate_kernel<<<ROWS / 4, 256, 0, stream>>>(X, Wg, bg, gate);
  dim3 gg(NPAD / 64, ROWS / 64);
  gemm_kernel<<<gg, 256, 0, stream>>>(Xbf, Wbf, bb, Y);
  recur_kernel<<<64, 512, 0, stream>>>(Y, gate, M0, out);
}

// Round 4
// 348.148 us; speedup vs baseline: 1.1966x; 1.1966x over previous
//
#include <hip/hip_runtime.h>
#include <stdint.h>

#define SEQ 256
#define BATCH 32
#define IN_DIM 1024
#define HID 64
#define NPAD 1280
#define ROWS (SEQ*BATCH)   // 8192

// workspace byte offsets (all 256B aligned)
#define XBF_OFF   0
#define WBF_OFF   16777216
#define BB_OFF    19398656
#define GATE_OFF  19403776
#define Y_OFF     19534848
// total ws use: 61,477,888 bytes

typedef __attribute__((ext_vector_type(8))) short short8;
typedef __attribute__((ext_vector_type(4))) float floatx4;

static __device__ __forceinline__ short f2bf(float f) {
  union { float f; uint32_t u; } a; a.f = f;
  uint32_t r = (a.u + 0x7FFFu + ((a.u >> 16) & 1u)) >> 16;  // RNE
  return (short)r;
}

// ---------------- prep: fp32 -> bf16 for X, concat+convert weights, concat bias ----------------
__global__ void prep_kernel(const float* __restrict__ X,
                            const float* __restrict__ Wk, const float* __restrict__ bk,
                            const float* __restrict__ Wv, const float* __restrict__ bv,
                            const float* __restrict__ Wg, const float* __restrict__ bg,
                            const float* __restrict__ Wq, const float* __restrict__ bq,
                            short* __restrict__ Xbf, short* __restrict__ Wbf,
                            float* __restrict__ bb)
{
  int64_t idx = (int64_t)blockIdx.x * blockDim.x + threadIdx.x;
  int64_t stride = (int64_t)gridDim.x * blockDim.x;
  const int64_t NX4 = (int64_t)ROWS * IN_DIM / 4;
  for (int64_t i = idx; i < NX4; i += stride) {
    float4 x = ((const float4*)X)[i];
    short4 s4;
    s4.x = f2bf(x.x); s4.y = f2bf(x.y); s4.z = f2bf(x.z); s4.w = f2bf(x.w);
    ((short4*)Xbf)[i] = s4;
  }
  const int64_t NW4 = (int64_t)NPAD * IN_DIM / 4;
  for (int64_t i = idx; i < NW4; i += stride) {
    int64_t e = i * 4;
    int r = (int)(e >> 10);
    int k = (int)(e & 1023);
    float4 x;
    if (r < 576)       x = *(const float4*)(Wk + (int64_t)r*1024 + k);
    else if (r < 1152) x = *(const float4*)(Wv + (int64_t)(r-576)*1024 + k);
    else if (r < 1216) x = *(const float4*)(Wq + (int64_t)(r-1152)*1024 + k);
    else               x = make_float4(0.f, 0.f, 0.f, 0.f);   // gate cols unused (fp32 gate kernel)
    short4 s4;
    s4.x = f2bf(x.x); s4.y = f2bf(x.y); s4.z = f2bf(x.z); s4.w = f2bf(x.w);
    ((short4*)Wbf)[i] = s4;
  }
  for (int64_t i = idx; i < NPAD; i += stride) {
    int r = (int)i; float v;
    if (r < 576)       v = bk[r];
    else if (r < 1152) v = bv[r - 576];
    else if (r < 1216) v = bq[r - 1152];
    else               v = 0.f;
    bb[r] = v;
  }
}

// ---------------- GEMM: Y[8192,1280] = Xbf @ Wbf^T + bb (bf16 MFMA, fp32 accum) ----------------
// 64x64 tile, BK=32, 256 threads (4 waves). Wave w -> N-subtile w; 4 M-subtiles each.
__global__ __launch_bounds__(256) void gemm_kernel(
    const short* __restrict__ Xbf,
    const short* __restrict__ Wbf,
    const float* __restrict__ bb,
    float* __restrict__ Y)
{
  __shared__ short8 AsV[256];  // 64 rows x 32 k, bf16
  __shared__ short8 BsV[256];
  short* As = (short*)AsV;
  short* Bs = (short*)BsV;

  const int tid  = threadIdx.x;
  const int lane = tid & 63;
  const int wv   = tid >> 6;     // 0..3
  const int quad = lane >> 4;    // 0..3
  const int cl   = lane & 15;
  const int m0 = blockIdx.y * 64;
  const int n0 = blockIdx.x * 64;

  // staging: each thread moves 16B (8 bf16) of A and of B per k-step
  const int srow = tid >> 2;         // 0..63
  const int scol = (tid & 3) * 8;    // 0,8,16,24
  const short* gA = Xbf + (int64_t)(m0 + srow) * IN_DIM + scol;
  const short* gB = Wbf + (int64_t)(n0 + srow) * IN_DIM + scol;
  short8* lA = (short8*)&As[srow * 32 + scol];
  short8* lB = (short8*)&Bs[srow * 32 + scol];

  floatx4 acc[4];
#pragma unroll
  for (int i = 0; i < 4; i++) acc[i] = (floatx4){0.f, 0.f, 0.f, 0.f};

  for (int ks = 0; ks < IN_DIM; ks += 32) {
    short8 ra = *(const short8*)(gA + ks);
    short8 rb = *(const short8*)(gB + ks);
    *lA = ra;
    *lB = rb;
    __syncthreads();
    short8 bfrag = *(const short8*)(&Bs[(wv * 16 + cl) * 32 + quad * 8]);
#pragma unroll
    for (int mt = 0; mt < 4; mt++) {
      short8 afrag = *(const short8*)(&As[(mt * 16 + cl) * 32 + quad * 8]);
      acc[mt] = __builtin_amdgcn_mfma_f32_16x16x32_bf16(afrag, bfrag, acc[mt], 0, 0, 0);
    }
    __syncthreads();
  }

  const int col = n0 + wv * 16 + cl;
  const float bias = bb[col];
#pragma unroll
  for (int mt = 0; mt < 4; mt++) {
#pragma unroll
    for (int r = 0; r < 4; r++) {
      int row = m0 + mt * 16 + quad * 4 + r;
      Y[(int64_t)row * NPAD + col] = acc[mt][r] + bias;
    }
  }
}

// ---------------- gate (fp32-exact): logits from X,Wg in fp32; top-2 + renormalized weights --------
// One wave per row. Lane l covers elements {i*256 + l*4 .. +3}, i=0..3 (float4, coalesced).
__global__ __launch_bounds__(256) void gate_kernel(
    const float* __restrict__ X,
    const float* __restrict__ Wg, const float* __restrict__ bg,
    float4* __restrict__ gate)
{
  const int lane = threadIdx.x & 63;
  const int row  = blockIdx.x * 4 + (threadIdx.x >> 6);
  const float* x = X + (int64_t)row * IN_DIM;

  float acc[8];
#pragma unroll
  for (int e = 0; e < 8; e++) acc[e] = 0.f;

#pragma unroll
  for (int i = 0; i < 4; i++) {
    const int off = i * 256 + lane * 4;
    float4 xv = *(const float4*)(x + off);
#pragma unroll
    for (int e = 0; e < 8; e++) {
      float4 wv = *(const float4*)(Wg + e * IN_DIM + off);
      acc[e] += xv.x * wv.x + xv.y * wv.y + xv.z * wv.z + xv.w * wv.w;
    }
  }
  // butterfly reduce each expert's partial across the 64 lanes
#pragma unroll
  for (int e = 0; e < 8; e++) {
#pragma unroll
    for (int m = 32; m >= 1; m >>= 1)
      acc[e] += __shfl_xor(acc[e], m);
    acc[e] += bg[e];
  }

  if (lane == 0) {
    int i0 = 0; float v0 = acc[0];
#pragma unroll
    for (int e = 1; e < 8; e++) if (acc[e] > v0) { v0 = acc[e]; i0 = e; }
    int i1 = -1; float v1 = -3.4e38f;
#pragma unroll
    for (int e = 0; e < 8; e++) if (e != i0 && acc[e] > v1) { v1 = acc[e]; i1 = e; }
    float e1 = __expf(v1 - v0);
    float inv = 1.f / (1.f + e1);
    gate[row] = make_float4(__int_as_float(i0), __int_as_float(i1), inv, e1 * inv);
  }
}

// 16-lane (DPP row) sum; result valid in lane (lane&15)==15 of each row.
static __device__ __forceinline__ float row16_sum(float x) {
  float r = x;
  r += __int_as_float(__builtin_amdgcn_update_dpp(0, __float_as_int(r), 0x118, 0xf, 0xf, false)); // row_shr:8
  r += __int_as_float(__builtin_amdgcn_update_dpp(0, __float_as_int(r), 0x114, 0xf, 0xf, false)); // row_shr:4
  r += __int_as_float(__builtin_amdgcn_update_dpp(0, __float_as_int(r), 0x112, 0xf, 0xf, false)); // row_shr:2
  r += __int_as_float(__builtin_amdgcn_update_dpp(0, __float_as_int(r), 0x111, 0xf, 0xf, false)); // row_shr:1
  return r;
}

// ---------------- recurrence: M register-resident, 2 j-split wgs per batch ----------------
// layout: lane&15 -> i-block (i = 4*(lane&15)+ii), lane>>4 + 4*wave + 32*jblk -> j
// R3 counters: 2450 cyc/step = Y-load latency (unhidden) + 4-stage ds_swizzle chain.
// This version: distance-2 register prefetch of all 7 Y loads (addresses from a
// distance-3 gate ring) + DPP row_shr reduction (VALU latency, no LDS pipe).
__global__ __launch_bounds__(512) void recur_kernel(
    const float* __restrict__ Y,
    const float4* __restrict__ gate,
    const float* __restrict__ M0,
    float* __restrict__ out)
{
  const int blk  = blockIdx.x;      // 0..63
  const int b    = blk >> 1;
  const int jblk = blk & 1;
  const int tid  = threadIdx.x;
  const int lane = tid & 63;
  const int wv   = tid >> 6;        // 0..7
  const int igrp = lane & 15;
  const int jloc = lane >> 4;
  const int j    = jblk * 32 + wv * 4 + jloc;
  const int ib   = igrp * 4;

  float M[9][4];
  const float* M0b = M0 + (int64_t)b * 9 * 4096;
#pragma unroll
  for (int m = 0; m < 9; m++)
#pragma unroll
    for (int ii = 0; ii < 4; ii++)
      M[m][ii] = M0b[m * 4096 + (ib + ii) * 64 + j];

  float* Mf = out + (int64_t)SEQ * BATCH * HID + (int64_t)b * 9 * 4096;

#define YROW(tt) (Y + ((int64_t)(tt) * BATCH + b) * NPAD)

#define LOAD_ROW(Yp, G, Q, K0, V0, KA, VA, KB, VB) {        \
    const int li0 = __float_as_int((G).x);                  \
    const int li1 = __float_as_int((G).y);                  \
    Q  = *(const float4*)((Yp) + 1152 + ib);                \
    K0 = *(const float4*)((Yp) + ib);                       \
    V0 = (Yp)[576 + j];                                     \
    KA = *(const float4*)((Yp) + li0 * 64 + ib);            \
    VA = (Yp)[576 + li0 * 64 + j];                          \
    KB = *(const float4*)((Yp) + li1 * 64 + ib);            \
    VB = (Yp)[576 + li1 * 64 + j]; }

#define DO_SLOT(mm, gw, KK, VV) {                                            \
      M[mm][0] += KK.x * VV; M[mm][1] += KK.y * VV;                          \
      M[mm][2] += KK.z * VV; M[mm][3] += KK.w * VV;                          \
      Mc0 += (gw) * M[mm][0]; Mc1 += (gw) * M[mm][1];                        \
      Mc2 += (gw) * M[mm][2]; Mc3 += (gw) * M[mm][3]; }

    // routed slot == 0: Mc captured M[0] after the shared update only; add this
    // routed delta unweighted too (reference does all scatter-adds before readout).
#define DO_SLOT0(gw, KK, VV) {                                               \
      float d0 = KK.x * VV, d1 = KK.y * VV, d2 = KK.z * VV, d3 = KK.w * VV;  \
      M[0][0] += d0; M[0][1] += d1; M[0][2] += d2; M[0][3] += d3;            \
      Mc0 += d0 + (gw) * M[0][0]; Mc1 += d1 + (gw) * M[0][1];                \
      Mc2 += d2 + (gw) * M[0][2]; Mc3 += d3 + (gw) * M[0][3]; }

#define COMPUTE(G, Q, K0, V0, KA, VA, KB, VB, TT) {                          \
    const int i0 = __float_as_int((G).x);                                    \
    const int i1 = __float_as_int((G).y);                                    \
    const float g0w = (G).z, g1w = (G).w;                                    \
    float Mc0, Mc1, Mc2, Mc3;                                                \
    M[0][0] += K0.x * V0; M[0][1] += K0.y * V0;                              \
    M[0][2] += K0.z * V0; M[0][3] += K0.w * V0;                              \
    Mc0 = M[0][0]; Mc1 = M[0][1]; Mc2 = M[0][2]; Mc3 = M[0][3];              \
    switch (i0) {                                                            \
      case 0: DO_SLOT0(g0w, KA, VA); break;                                  \
      case 1: DO_SLOT(1, g0w, KA, VA); break;                                \
      case 2: DO_SLOT(2, g0w, KA, VA); break;                                \
      case 3: DO_SLOT(3, g0w, KA, VA); break;                                \
      case 4: DO_SLOT(4, g0w, KA, VA); break;                                \
      case 5: DO_SLOT(5, g0w, KA, VA); break;                                \
      case 6: DO_SLOT(6, g0w, KA, VA); break;                                \
      default: DO_SLOT(7, g0w, KA, VA); break;                               \
    }                                                                        \
    switch (i1) {                                                            \
      case 0: DO_SLOT0(g1w, KB, VB); break;                                  \
      case 1: DO_SLOT(1, g1w, KB, VB); break;                                \
      case 2: DO_SLOT(2, g1w, KB, VB); break;                                \
      case 3: DO_SLOT(3, g1w, KB, VB); break;                                \
      case 4: DO_SLOT(4, g1w, KB, VB); break;                                \
      case 5: DO_SLOT(5, g1w, KB, VB); break;                                \
      case 6: DO_SLOT(6, g1w, KB, VB); break;                                \
      default: DO_SLOT(7, g1w, KB, VB); break;                               \
    }                                                                        \
    float part = Q.x * Mc0 + Q.y * Mc1 + Q.z * Mc2 + Q.w * Mc3;              \
    part = row16_sum(part);                                                  \
    if (igrp == 15)                                                          \
      out[(int64_t)(TT) * (BATCH * HID) + b * HID + j] = part; }

  // gate ring: g0=gate[t], g1=gate[t+1], g2=gate[t+2]
  float4 g0 = gate[0 * BATCH + b];
  float4 g1 = gate[1 * BATCH + b];
  float4 g2 = gate[2 * BATCH + b];

  // prefetch buffers (distance 2)
  float4 q0v, k00, ka0, kb0; float v00, va0, vb0;
  float4 q1v, k01, ka1, kb1; float v01, va1, vb1;
  LOAD_ROW(YROW(0), g0, q0v, k00, v00, ka0, va0, kb0, vb0);
  LOAD_ROW(YROW(1), g1, q1v, k01, v01, ka1, va1, kb1, vb1);

  for (int t = 0; t < SEQ; t += 2) {
    { // even step t: consume buf0, prefetch t+2 into buf0
      const int tl = (t + 2 < SEQ) ? t + 2 : SEQ - 1;
      const int tg = (t + 3 < SEQ) ? t + 3 : SEQ - 1;
      float4 gnew = gate[tg * BATCH + b];
      float4 nq, nk0, nka, nkb; float nv0, nva, nvb;
      LOAD_ROW(YROW(tl), g2, nq, nk0, nv0, nka, nva, nkb, nvb);
      COMPUTE(g0, q0v, k00, v00, ka0, va0, kb0, vb0, t);
      q0v = nq; k00 = nk0; v00 = nv0; ka0 = nka; va0 = nva; kb0 = nkb; vb0 = nvb;
      g0 = g1; g1 = g2; g2 = gnew;
    }
    { // odd step t+1: consume buf1, prefetch t+3 into buf1
      const int tl = (t + 3 < SEQ) ? t + 3 : SEQ - 1;
      const int tg = (t + 4 < SEQ) ? t + 4 : SEQ - 1;
      float4 gnew = gate[tg * BATCH + b];
      float4 nq, nk0, nka, nkb; float nv0, nva, nvb;
      LOAD_ROW(YROW(tl), g2, nq, nk0, nv0, nka, nva, nkb, nvb);
      COMPUTE(g0, q1v, k01, v01, ka1, va1, kb1, vb1, t + 1);
      q1v = nq; k01 = nk0; v01 = nv0; ka1 = nka; va1 = nva; kb1 = nkb; vb1 = nvb;
      g0 = g1; g1 = g2; g2 = gnew;
    }
  }
#undef COMPUTE
#undef DO_SLOT
#undef DO_SLOT0
#undef LOAD_ROW
#undef YROW

#pragma unroll
  for (int m = 0; m < 9; m++)
#pragma unroll
    for (int ii = 0; ii < 4; ii++)
      Mf[m * 4096 + (ib + ii) * 64 + j] = M[m][ii];
}

// ---------------- launch ----------------
extern "C" void kernel_launch(void* const* d_in, const int* in_sizes, int n_in,
                              void* d_out, int out_size, void* d_ws, size_t ws_size,
                              hipStream_t stream)
{
  const float* X  = (const float*)d_in[0];
  const float* M0 = (const float*)d_in[1];
  const float* Wk = (const float*)d_in[2];
  const float* bk = (const float*)d_in[3];
  const float* Wv = (const float*)d_in[4];
  const float* bv = (const float*)d_in[5];
  const float* Wg = (const float*)d_in[6];
  const float* bg = (const float*)d_in[7];
  const float* Wq = (const float*)d_in[8];
  const float* bq = (const float*)d_in[9];

  char* ws = (char*)d_ws;
  short*  Xbf  = (short*)(ws + XBF_OFF);
  short*  Wbf  = (short*)(ws + WBF_OFF);
  float*  bb   = (float*)(ws + BB_OFF);
  float4* gate = (float4*)(ws + GATE_OFF);
  float*  Y    = (float*)(ws + Y_OFF);
  float*  out  = (float*)d_out;

  prep_kernel<<<2048, 256, 0, stream>>>(X, Wk, bk, Wv, bv, Wg, bg, Wq, bq, Xbf, Wbf, bb);
  gate_kernel<<<ROWS / 4, 256, 0, stream>>>(X, Wg, bg, gate);
  dim3 gg(NPAD / 64, ROWS / 64);
  gemm_kernel<<<gg, 256, 0, stream>>>(Xbf, Wbf, bb, Y);
  recur_kernel<<<64, 512, 0, stream>>>(Y, gate, M0, out);
}

// Round 5
// 328.534 us; speedup vs baseline: 1.2681x; 1.0597x over previous
//
#include <hip/hip_runtime.h>
#include <stdint.h>

#define SEQ 256
#define BATCH 32
#define IN_DIM 1024
#define HID 64
#define NPAD 1280
#define ROWS (SEQ*BATCH)   // 8192

// workspace byte offsets (all 256B aligned)
#define XBF_OFF   0
#define WBF_OFF   16777216
#define BB_OFF    19398656
#define GATE_OFF  19403776
#define Y_OFF     19534848
// total ws use: 61,477,888 bytes

typedef __attribute__((ext_vector_type(8))) short short8;
typedef __attribute__((ext_vector_type(4))) float floatx4;

static __device__ __forceinline__ short f2bf(float f) {
  union { float f; uint32_t u; } a; a.f = f;
  uint32_t r = (a.u + 0x7FFFu + ((a.u >> 16) & 1u)) >> 16;  // RNE
  return (short)r;
}

// ---------------- prep: fp32 -> bf16 for X, concat+convert weights, concat bias ----------------
__global__ void prep_kernel(const float* __restrict__ X,
                            const float* __restrict__ Wk, const float* __restrict__ bk,
                            const float* __restrict__ Wv, const float* __restrict__ bv,
                            const float* __restrict__ Wg, const float* __restrict__ bg,
                            const float* __restrict__ Wq, const float* __restrict__ bq,
                            short* __restrict__ Xbf, short* __restrict__ Wbf,
                            float* __restrict__ bb)
{
  int64_t idx = (int64_t)blockIdx.x * blockDim.x + threadIdx.x;
  int64_t stride = (int64_t)gridDim.x * blockDim.x;
  const int64_t NX4 = (int64_t)ROWS * IN_DIM / 4;
  for (int64_t i = idx; i < NX4; i += stride) {
    float4 x = ((const float4*)X)[i];
    short4 s4;
    s4.x = f2bf(x.x); s4.y = f2bf(x.y); s4.z = f2bf(x.z); s4.w = f2bf(x.w);
    ((short4*)Xbf)[i] = s4;
  }
  const int64_t NW4 = (int64_t)NPAD * IN_DIM / 4;
  for (int64_t i = idx; i < NW4; i += stride) {
    int64_t e = i * 4;
    int r = (int)(e >> 10);
    int k = (int)(e & 1023);
    float4 x;
    if (r < 576)       x = *(const float4*)(Wk + (int64_t)r*1024 + k);
    else if (r < 1152) x = *(const float4*)(Wv + (int64_t)(r-576)*1024 + k);
    else if (r < 1216) x = *(const float4*)(Wq + (int64_t)(r-1152)*1024 + k);
    else               x = make_float4(0.f, 0.f, 0.f, 0.f);   // gate cols unused (fp32 gate kernel)
    short4 s4;
    s4.x = f2bf(x.x); s4.y = f2bf(x.y); s4.z = f2bf(x.z); s4.w = f2bf(x.w);
    ((short4*)Wbf)[i] = s4;
  }
  for (int64_t i = idx; i < NPAD; i += stride) {
    int r = (int)i; float v;
    if (r < 576)       v = bk[r];
    else if (r < 1152) v = bv[r - 576];
    else if (r < 1216) v = bq[r - 1152];
    else               v = 0.f;
    bb[r] = v;
  }
}

// ---------------- GEMM: Y[8192,1280] = Xbf @ Wbf^T + bb (bf16 MFMA, fp32 accum) ----------------
// 64x64 tile, BK=32, 256 threads (4 waves). Wave w -> N-subtile w; 4 M-subtiles each.
__global__ __launch_bounds__(256) void gemm_kernel(
    const short* __restrict__ Xbf,
    const short* __restrict__ Wbf,
    const float* __restrict__ bb,
    float* __restrict__ Y)
{
  __shared__ short8 AsV[256];  // 64 rows x 32 k, bf16
  __shared__ short8 BsV[256];
  short* As = (short*)AsV;
  short* Bs = (short*)BsV;

  const int tid  = threadIdx.x;
  const int lane = tid & 63;
  const int wv   = tid >> 6;     // 0..3
  const int quad = lane >> 4;    // 0..3
  const int cl   = lane & 15;
  const int m0 = blockIdx.y * 64;
  const int n0 = blockIdx.x * 64;

  // staging: each thread moves 16B (8 bf16) of A and of B per k-step
  const int srow = tid >> 2;         // 0..63
  const int scol = (tid & 3) * 8;    // 0,8,16,24
  const short* gA = Xbf + (int64_t)(m0 + srow) * IN_DIM + scol;
  const short* gB = Wbf + (int64_t)(n0 + srow) * IN_DIM + scol;
  short8* lA = (short8*)&As[srow * 32 + scol];
  short8* lB = (short8*)&Bs[srow * 32 + scol];

  floatx4 acc[4];
#pragma unroll
  for (int i = 0; i < 4; i++) acc[i] = (floatx4){0.f, 0.f, 0.f, 0.f};

  for (int ks = 0; ks < IN_DIM; ks += 32) {
    short8 ra = *(const short8*)(gA + ks);
    short8 rb = *(const short8*)(gB + ks);
    *lA = ra;
    *lB = rb;
    __syncthreads();
    short8 bfrag = *(const short8*)(&Bs[(wv * 16 + cl) * 32 + quad * 8]);
#pragma unroll
    for (int mt = 0; mt < 4; mt++) {
      short8 afrag = *(const short8*)(&As[(mt * 16 + cl) * 32 + quad * 8]);
      acc[mt] = __builtin_amdgcn_mfma_f32_16x16x32_bf16(afrag, bfrag, acc[mt], 0, 0, 0);
    }
    __syncthreads();
  }

  const int col = n0 + wv * 16 + cl;
  const float bias = bb[col];
#pragma unroll
  for (int mt = 0; mt < 4; mt++) {
#pragma unroll
    for (int r = 0; r < 4; r++) {
      int row = m0 + mt * 16 + quad * 4 + r;
      Y[(int64_t)row * NPAD + col] = acc[mt][r] + bias;
    }
  }
}

// ---------------- gate (fp32-exact): logits from X,Wg in fp32; top-2 + renormalized weights --------
// One wave per row. Lane l covers elements {i*256 + l*4 .. +3}, i=0..3 (float4, coalesced).
__global__ __launch_bounds__(256) void gate_kernel(
    const float* __restrict__ X,
    const float* __restrict__ Wg, const float* __restrict__ bg,
    float4* __restrict__ gate)
{
  const int lane = threadIdx.x & 63;
  const int row  = blockIdx.x * 4 + (threadIdx.x >> 6);
  const float* x = X + (int64_t)row * IN_DIM;

  float acc[8];
#pragma unroll
  for (int e = 0; e < 8; e++) acc[e] = 0.f;

#pragma unroll
  for (int i = 0; i < 4; i++) {
    const int off = i * 256 + lane * 4;
    float4 xv = *(const float4*)(x + off);
#pragma unroll
    for (int e = 0; e < 8; e++) {
      float4 wv = *(const float4*)(Wg + e * IN_DIM + off);
      acc[e] += xv.x * wv.x + xv.y * wv.y + xv.z * wv.z + xv.w * wv.w;
    }
  }
  // butterfly reduce each expert's partial across the 64 lanes
#pragma unroll
  for (int e = 0; e < 8; e++) {
#pragma unroll
    for (int m = 32; m >= 1; m >>= 1)
      acc[e] += __shfl_xor(acc[e], m);
    acc[e] += bg[e];
  }

  if (lane == 0) {
    int i0 = 0; float v0 = acc[0];
#pragma unroll
    for (int e = 1; e < 8; e++) if (acc[e] > v0) { v0 = acc[e]; i0 = e; }
    int i1 = -1; float v1 = -3.4e38f;
#pragma unroll
    for (int e = 0; e < 8; e++) if (e != i0 && acc[e] > v1) { v1 = acc[e]; i1 = e; }
    float e1 = __expf(v1 - v0);
    float inv = 1.f / (1.f + e1);
    gate[row] = make_float4(__int_as_float(i0), __int_as_float(i1), inv, e1 * inv);
  }
}

// 16-lane (DPP row) sum; result valid in lane (lane&15)==15 of each row.
static __device__ __forceinline__ float row16_sum(float x) {
  float r = x;
  r += __int_as_float(__builtin_amdgcn_update_dpp(0, __float_as_int(r), 0x118, 0xf, 0xf, false)); // row_shr:8
  r += __int_as_float(__builtin_amdgcn_update_dpp(0, __float_as_int(r), 0x114, 0xf, 0xf, false)); // row_shr:4
  r += __int_as_float(__builtin_amdgcn_update_dpp(0, __float_as_int(r), 0x112, 0xf, 0xf, false)); // row_shr:2
  r += __int_as_float(__builtin_amdgcn_update_dpp(0, __float_as_int(r), 0x111, 0xf, 0xf, false)); // row_shr:1
  return r;
}

// ---------------- recurrence: M register-resident, 2 j-split wgs per batch ----------------
// layout: lane&15 -> i-block (i = 4*(lane&15)+ii), lane>>4 + 4*wave + 32*jblk -> j
// R4 post-mortem: distance-2 pipeline was defeated by the register copies right
// after COMPUTE (forced vmcnt wait ~1 COMPUTE after issue). This version: true
// depth-4 pipeline, unroll-8 with static buffer slots (no copies) + depth-8 gate
// ring. The vmcnt wait for a row now sits 3 COMPUTE phases (~450+ cyc) after issue.
__global__ __launch_bounds__(512) void recur_kernel(
    const float* __restrict__ Y,
    const float4* __restrict__ gate,
    const float* __restrict__ M0,
    float* __restrict__ out)
{
  const int blk  = blockIdx.x;      // 0..63
  const int b    = blk >> 1;
  const int jblk = blk & 1;
  const int tid  = threadIdx.x;
  const int lane = tid & 63;
  const int wv   = tid >> 6;        // 0..7
  const int igrp = lane & 15;
  const int jloc = lane >> 4;
  const int j    = jblk * 32 + wv * 4 + jloc;
  const int ib   = igrp * 4;

  float M[9][4];
  const float* M0b = M0 + (int64_t)b * 9 * 4096;
#pragma unroll
  for (int m = 0; m < 9; m++)
#pragma unroll
    for (int ii = 0; ii < 4; ii++)
      M[m][ii] = M0b[m * 4096 + (ib + ii) * 64 + j];

  float* Mf = out + (int64_t)SEQ * BATCH * HID + (int64_t)b * 9 * 4096;

  struct Buf { float4 q, k0, ka, kb; float v0, va, vb; };
  Buf bf[4];
  float4 gr[8];

#define YROW(tt) (Y + ((int64_t)(tt) * BATCH + b) * NPAD)

#define LOAD_ROW(BF, Yp, G) {                               \
    const int li0 = __float_as_int((G).x);                  \
    const int li1 = __float_as_int((G).y);                  \
    (BF).q  = *(const float4*)((Yp) + 1152 + ib);           \
    (BF).k0 = *(const float4*)((Yp) + ib);                  \
    (BF).v0 = (Yp)[576 + j];                                \
    (BF).ka = *(const float4*)((Yp) + li0 * 64 + ib);       \
    (BF).va = (Yp)[576 + li0 * 64 + j];                     \
    (BF).kb = *(const float4*)((Yp) + li1 * 64 + ib);       \
    (BF).vb = (Yp)[576 + li1 * 64 + j]; }

#define DO_SLOT(mm, gw, KK, VV) {                                            \
      M[mm][0] += KK.x * VV; M[mm][1] += KK.y * VV;                          \
      M[mm][2] += KK.z * VV; M[mm][3] += KK.w * VV;                          \
      Mc0 += (gw) * M[mm][0]; Mc1 += (gw) * M[mm][1];                        \
      Mc2 += (gw) * M[mm][2]; Mc3 += (gw) * M[mm][3]; }

    // routed slot == 0: Mc captured M[0] after the shared update only; add this
    // routed delta unweighted too (reference does all scatter-adds before readout).
#define DO_SLOT0(gw, KK, VV) {                                               \
      float d0 = KK.x * VV, d1 = KK.y * VV, d2 = KK.z * VV, d3 = KK.w * VV;  \
      M[0][0] += d0; M[0][1] += d1; M[0][2] += d2; M[0][3] += d3;            \
      Mc0 += d0 + (gw) * M[0][0]; Mc1 += d1 + (gw) * M[0][1];                \
      Mc2 += d2 + (gw) * M[0][2]; Mc3 += d3 + (gw) * M[0][3]; }

#define COMPUTE(BF, G, TT) {                                                 \
    const int i0 = __float_as_int((G).x);                                    \
    const int i1 = __float_as_int((G).y);                                    \
    const float g0w = (G).z, g1w = (G).w;                                    \
    float Mc0, Mc1, Mc2, Mc3;                                                \
    M[0][0] += (BF).k0.x * (BF).v0; M[0][1] += (BF).k0.y * (BF).v0;          \
    M[0][2] += (BF).k0.z * (BF).v0; M[0][3] += (BF).k0.w * (BF).v0;          \
    Mc0 = M[0][0]; Mc1 = M[0][1]; Mc2 = M[0][2]; Mc3 = M[0][3];              \
    switch (i0) {                                                            \
      case 0: DO_SLOT0(g0w, (BF).ka, (BF).va); break;                        \
      case 1: DO_SLOT(1, g0w, (BF).ka, (BF).va); break;                      \
      case 2: DO_SLOT(2, g0w, (BF).ka, (BF).va); break;                      \
      case 3: DO_SLOT(3, g0w, (BF).ka, (BF).va); break;                      \
      case 4: DO_SLOT(4, g0w, (BF).ka, (BF).va); break;                      \
      case 5: DO_SLOT(5, g0w, (BF).ka, (BF).va); break;                      \
      case 6: DO_SLOT(6, g0w, (BF).ka, (BF).va); break;                      \
      default: DO_SLOT(7, g0w, (BF).ka, (BF).va); break;                     \
    }                                                                        \
    switch (i1) {                                                            \
      case 0: DO_SLOT0(g1w, (BF).kb, (BF).vb); break;                        \
      case 1: DO_SLOT(1, g1w, (BF).kb, (BF).vb); break;                      \
      case 2: DO_SLOT(2, g1w, (BF).kb, (BF).vb); break;                      \
      case 3: DO_SLOT(3, g1w, (BF).kb, (BF).vb); break;                      \
      case 4: DO_SLOT(4, g1w, (BF).kb, (BF).vb); break;                      \
      case 5: DO_SLOT(5, g1w, (BF).kb, (BF).vb); break;                      \
      case 6: DO_SLOT(6, g1w, (BF).kb, (BF).vb); break;                      \
      default: DO_SLOT(7, g1w, (BF).kb, (BF).vb); break;                     \
    }                                                                        \
    float part = (BF).q.x * Mc0 + (BF).q.y * Mc1 +                           \
                 (BF).q.z * Mc2 + (BF).q.w * Mc3;                            \
    part = row16_sum(part);                                                  \
    if (igrp == 15)                                                          \
      out[(int64_t)(TT) * (BATCH * HID) + b * HID + j] = part; }

  // prologue: gr[i] = gate[i], bf[i] = row i (via gr[i])
#pragma unroll
  for (int i = 0; i < 8; i++) gr[i] = gate[i * BATCH + b];
#pragma unroll
  for (int i = 0; i < 4; i++) LOAD_ROW(bf[i], YROW(i), gr[i]);

  // invariant at loop top (t multiple of 8): gr[p]=gate[t+p], bf[p&3]=row t+p (p<4)
#define PHASE(P) {                                                           \
    COMPUTE(bf[(P) & 3], gr[P], t + (P));                                    \
    int tg = t + (P) + 8; if (tg > SEQ - 1) tg = SEQ - 1;                    \
    gr[P] = gate[tg * BATCH + b];      /* dead after COMPUTE; refill */      \
    int tl = t + (P) + 4; if (tl > SEQ - 1) tl = SEQ - 1;                    \
    LOAD_ROW(bf[(P) & 3], YROW(tl), ((P) < 4 ? gr[(P) + 4] : gr[(P) - 4])); }

  for (int t = 0; t < SEQ; t += 8) {
    PHASE(0) PHASE(1) PHASE(2) PHASE(3)
    PHASE(4) PHASE(5) PHASE(6) PHASE(7)
  }
#undef PHASE
#undef COMPUTE
#undef DO_SLOT
#undef DO_SLOT0
#undef LOAD_ROW
#undef YROW

#pragma unroll
  for (int m = 0; m < 9; m++)
#pragma unroll
    for (int ii = 0; ii < 4; ii++)
      Mf[m * 4096 + (ib + ii) * 64 + j] = M[m][ii];
}

// ---------------- launch ----------------
extern "C" void kernel_launch(void* const* d_in, const int* in_sizes, int n_in,
                              void* d_out, int out_size, void* d_ws, size_t ws_size,
                              hipStream_t stream)
{
  const float* X  = (const float*)d_in[0];
  const float* M0 = (const float*)d_in[1];
  const float* Wk = (const float*)d_in[2];
  const float* bk = (const float*)d_in[3];
  const float* Wv = (const float*)d_in[4];
  const float* bv = (const float*)d_in[5];
  const float* Wg = (const float*)d_in[6];
  const float* bg = (const float*)d_in[7];
  const float* Wq = (const float*)d_in[8];
  const float* bq = (const float*)d_in[9];

  char* ws = (char*)d_ws;
  short*  Xbf  = (short*)(ws + XBF_OFF);
  short*  Wbf  = (short*)(ws + WBF_OFF);
  float*  bb   = (float*)(ws + BB_OFF);
  float4* gate = (float4*)(ws + GATE_OFF);
  float*  Y    = (float*)(ws + Y_OFF);
  float*  out  = (float*)d_out;

  prep_kernel<<<2048, 256, 0, stream>>>(X, Wk, bk, Wv, bv, Wg, bg, Wq, bq, Xbf, Wbf, bb);
  gate_kernel<<<ROWS / 4, 256, 0, stream>>>(X, Wg, bg, gate);
  dim3 gg(NPAD / 64, ROWS / 64);
  gemm_kernel<<<gg, 256, 0, stream>>>(Xbf, Wbf, bb, Y);
  recur_kernel<<<64, 512, 0, stream>>>(Y, gate, M0, out);
}